// Round 11
// baseline (278.794 us; speedup 1.0000x reference)
//
#include <hip/hip_runtime.h>

typedef __attribute__((ext_vector_type(8))) short short8;
typedef __attribute__((ext_vector_type(4))) short short4v;
typedef __attribute__((ext_vector_type(4))) float float4v;

#define MFMA16(a, b, c) __builtin_amdgcn_mfma_f32_16x16x32_bf16((a), (b), (c), 0, 0, 0)

constexpr int kThreads = 1024;  // 16 waves -> 4 waves/SIMD at 1 block/CU
// LDS (ushort units):
//   [0,     32768)  K2 : pos-major; 8 granules of 16B per pos-row.
//                   granule g = cp*4+quad (XOR pos&7); content
//                   [K[pos][cp*32+quad*4+0..3], K[pos][cp*32+16+quad*4+0..3]]
//   [32768, 65536)  V2 : d-major; granule [qg][kp] with kp-field XOR (d&7) XOR qg;
//                   content [V[kp*32+qg*4+0..3][d], V[kp*32+16+qg*4+0..3][d]]
//   [65536, 77824)  Wq^T/Wk^T/Wv^T staging (3 x 4096), 8-consecutive-d b128 frags
//   [77824, 81920)  Wd2 : e-major; granule g = cp*4+quad (XOR e&7)
constexpr int LDS_TOTAL_BYTES = 163840;  // 160 KiB -> 1 block/CU
// LAUNCH BOUNDS (hard-won, r10): declare ONLY the block size. A 1024-thread
// block already forces 4 waves/SIMD co-resident -> compiler caps VGPR at 128
// for launchability. Adding a second argument ("4") made the toolchain target
// 64 VGPR (CUDA min-blocks interpretation) -> 1.4 KB/thread scratch spill,
// hbm 1.9e8 -> 5.7e8 B, dur 106 -> 186 us. Never over-constrain it.
// REGISTER BUDGET: allocator behaves cleanly at <=128 arch VGPRs here (r8).
// Phase-2 peak live (S-window 4 tiles x 2 q-tiles = 32 regs + o 32 + Q 16)
// is unchanged from the clean r8 build; phase-1 live set is smaller.

static __device__ __forceinline__ unsigned short f2bf(float f) {
  // native cast -> HW v_cvt_pk_bf16_f32 (RNE); passed absmax in r10
  __bf16 h = (__bf16)f;
  return __builtin_bit_cast(unsigned short, h);
}

// W^T staging swizzle for phase 1 (b128 frags of 8 consecutive d).
static __device__ __forceinline__ int wsw_idx(int e, int d) {
  return ((((d >> 3) << 9) + (e << 3) + (d & 7)) ^ (((d >> 3) & 3) << 3));
}

__global__ __launch_bounds__(kThreads) void ts_attn_fused(
    const float* __restrict__ x, const float* __restrict__ Wq_t,
    const float* __restrict__ Wk_t, const float* __restrict__ Wv_t,
    const float* __restrict__ Wq_s, const float* __restrict__ Wk_s,
    const float* __restrict__ Wv_s, const float* __restrict__ Wd_t,
    const float* __restrict__ bd_t, const float* __restrict__ Wd_s,
    const float* __restrict__ bd_s, float* __restrict__ out,
    unsigned short* __restrict__ qws) {
  extern __shared__ __align__(16) unsigned short smem[];
  unsigned short* Ksw = smem;            // 32768 us
  unsigned short* Vsw = smem + 32768;    // 32768 us
  unsigned short* Wst = smem + 65536;    // 12288 us (3 x 4096)
  unsigned short* Wdsw = smem + 77824;   // 4096 us

  const int tid = threadIdx.x;
  const int wv = tid >> 6;    // wave 0..15
  const int lane = tid & 63;
  const int ln = lane & 15;   // q position within 16-tile
  const int quad = lane >> 4;
  const int e8 = ln & 7;      // lane-constant XOR key (pos&7 / e&7 of this lane's rows)
  const int b = blockIdx.x;

  const float* xb = x + (size_t)b * (512 * 64);
  float* outb = out + (size_t)b * (512 * 64);
  unsigned short* qg = qws + (size_t)b * (512 * 64);  // Q bf16 in slot-group order

#pragma unroll 1
  for (int br = 0; br < 2; ++br) {
    const float* Wq = br ? Wq_s : Wq_t;
    const float* Wk = br ? Wk_s : Wk_t;
    const float* Wv = br ? Wv_s : Wv_t;
    const float* Wd = br ? Wd_s : Wd_t;

    // ---- stage weight matrices into LDS (bf16); 4 elems/thread ----
    {
      const int d = tid >> 4;        // 0..63
      const int e0 = (tid & 15) * 4; // 0..60
      const float* srcs[3] = {Wq, Wk, Wv};
#pragma unroll
      for (int g = 0; g < 3; ++g) {
        const float4v u = *reinterpret_cast<const float4v*>(srcs[g] + d * 64 + e0);
        unsigned short* dst = Wst + g * 4096;
#pragma unroll
        for (int i = 0; i < 4; ++i) dst[wsw_idx(e0 + i, d)] = f2bf(u[i]);
      }
      // Wd -> Wd2 slot-group layout: d -> (cp, quad_g, h)
      const int cp_ = d >> 5;
      const int c = d & 31;
      const int qd_ = (c >> 2) & 3;
      const int h_ = ((c >> 4) << 2) | (c & 3);
      const int gbase = (cp_ * 4 + qd_);
      const float4v u = *reinterpret_cast<const float4v*>(Wd + d * 64 + e0);
#pragma unroll
      for (int i = 0; i < 4; ++i) {
        const int e = e0 + i;
        Wdsw[e * 64 + ((gbase ^ (e & 7)) << 3) + h_] = f2bf(u[i]);
      }
    }
    __syncthreads();

    // ---- phase 1: Q^T,K^T,V^T = W^T @ X^T. Q -> global ws; K,V -> LDS ----
#pragma unroll 1
    for (int mi = 0; mi < 2; ++mi) {
      const int mrow = (wv + mi * 16) * 16 + ln;
      // V2 decomposition of this row's position (for g==2 writes)
      const int kpq = mrow >> 5;
      const int w5 = mrow & 31;
      const int jj = ((w5 >> 4) << 2) | (w5 & 3);
      const int qg2 = (w5 >> 2) & 3;
      short8 xa0, xa1;  // X^T B-frags (native 8-run: slot j -> d = cc*32 + quad*8 + j)
      {
        const float4v u0 = *reinterpret_cast<const float4v*>(xb + mrow * 64 + quad * 8);
        const float4v v0 = *reinterpret_cast<const float4v*>(xb + mrow * 64 + quad * 8 + 4);
        const float4v u1 = *reinterpret_cast<const float4v*>(xb + mrow * 64 + 32 + quad * 8);
        const float4v v1 = *reinterpret_cast<const float4v*>(xb + mrow * 64 + 32 + quad * 8 + 4);
#pragma unroll
        for (int i = 0; i < 4; ++i) {
          xa0[i] = (short)f2bf(u0[i]);
          xa0[4 + i] = (short)f2bf(v0[i]);
          xa1[i] = (short)f2bf(u1[i]);
          xa1[4 + i] = (short)f2bf(v1[i]);
        }
      }
#pragma unroll
      for (int g = 0; g < 3; ++g) {
        const unsigned short* Wg = Wst + g * 4096;
#pragma unroll
        for (int nt = 0; nt < 4; ++nt) {
          const short8 w0 = *reinterpret_cast<const short8*>(Wg + wsw_idx(nt * 16 + ln, quad * 8));
          const short8 w1 = *reinterpret_cast<const short8*>(Wg + wsw_idx(nt * 16 + ln, 32 + quad * 8));
          float4v acc = {0.f, 0.f, 0.f, 0.f};
          acc = MFMA16(w0, xa0, acc);
          acc = MFMA16(w1, xa1, acc);
          // D-frag: acc[r] = M[mrow][e = nt*16 + quad*4 + r]
          if (g == 0) {
            short4v pk;
#pragma unroll
            for (int r = 0; r < 4; ++r) pk[r] = (short)f2bf(acc[r]);
            *reinterpret_cast<short4v*>(
                qg + mrow * 64 + (nt >> 1) * 32 + quad * 8 + (nt & 1) * 4) = pk;
          } else if (g == 1) {
            short4v pk;
#pragma unroll
            for (int r = 0; r < 4; ++r) pk[r] = (short)f2bf(acc[r]);
            const int gswz = ((nt >> 1) * 4 + quad) ^ (mrow & 7);
            *reinterpret_cast<short4v*>(
                Ksw + mrow * 64 + (gswz << 3) + (nt & 1) * 4) = pk;
          } else {
            // V write: granule field XOR qg2 spreads the 16-lane store across
            // 4 bank-groups (was 8-way conflict in 2 banks without it).
#pragma unroll
            for (int r = 0; r < 4; ++r) {
              const int d = nt * 16 + quad * 4 + r;
              const int gv = (kpq ^ (d & 7) ^ qg2);
              Vsw[(d << 9) + (qg2 << 7) + (gv << 3) + jj] = f2bf(acc[r]);
            }
          }
        }
      }
    }
    __syncthreads();

    // ---- phase 2: each wave owns q-tile pair (A: wv, B: wv+16) ----
    // K/V/Wd ds_reads feed both tiles; dual softmax chains give ILP.
    // Online softmax window = 4 K-tiles (64 pos) -> sA[4]+sB[4] = 32 live regs.
    {
      const int qtA = wv;
      const int qtB = wv + 16;
      const unsigned short* qrowA = qg + (qtA * 16 + ln) * 64;
      const unsigned short* qrowB = qg + (qtB * 16 + ln) * 64;
      const short8 qaA = *reinterpret_cast<const short8*>(qrowA + quad * 8);
      const short8 qbA = *reinterpret_cast<const short8*>(qrowA + 32 + quad * 8);
      const short8 qaB = *reinterpret_cast<const short8*>(qrowB + quad * 8);
      const short8 qbB = *reinterpret_cast<const short8*>(qrowB + 32 + quad * 8);

      const int kb0 = ln * 64 + ((quad ^ e8) << 3);        // cp=0 granule
      const int kb1 = ln * 64 + (((4 + quad) ^ e8) << 3);  // cp=1 granule
      const int vxor = (quad << 3) ^ (e8 << 3);            // V read granule XOR

      float4v oA[4], oB[4];
#pragma unroll
      for (int i = 0; i < 4; ++i) {
        oA[i] = (float4v){0.f, 0.f, 0.f, 0.f};
        oB[i] = (float4v){0.f, 0.f, 0.f, 0.f};
      }
      float mrunA = -3.0e38f, mrunB = -3.0e38f;
      float sumA = 0.f, sumB = 0.f;

#pragma unroll 1
      for (int ch = 0; ch < 8; ++ch) {
        // S chunks for both tiles: s*[k8][r], pos = (ch*4+k8)*16 + quad*4 + r
        float4v sA[4], sB[4];
#pragma unroll
        for (int k8 = 0; k8 < 4; ++k8) {
          const int kt = ch * 4 + k8;
          const short8 k0 = *reinterpret_cast<const short8*>(Ksw + kt * 1024 + kb0);
          const short8 k1 = *reinterpret_cast<const short8*>(Ksw + kt * 1024 + kb1);
          float4v aA = {0.f, 0.f, 0.f, 0.f};
          aA = MFMA16(k0, qaA, aA);
          aA = MFMA16(k1, qbA, aA);
          sA[k8] = aA;
          float4v aB = {0.f, 0.f, 0.f, 0.f};
          aB = MFMA16(k0, qaB, aB);
          aB = MFMA16(k1, qbB, aB);
          sB[k8] = aB;
        }

        // chunk max per tile (independent serial chains -> good dual issue)
        float4v m4A = sA[0], m4B = sB[0];
#pragma unroll
        for (int k8 = 1; k8 < 4; ++k8)
#pragma unroll
          for (int r = 0; r < 4; ++r) {
            m4A[r] = fmaxf(m4A[r], sA[k8][r]);
            m4B[r] = fmaxf(m4B[r], sB[k8][r]);
          }
        float cmxA = fmaxf(fmaxf(m4A[0], m4A[1]), fmaxf(m4A[2], m4A[3]));
        float cmxB = fmaxf(fmaxf(m4B[0], m4B[1]), fmaxf(m4B[2], m4B[3]));
        cmxA = fmaxf(cmxA, __shfl_xor(cmxA, 16, 64));
        cmxB = fmaxf(cmxB, __shfl_xor(cmxB, 16, 64));
        cmxA = fmaxf(cmxA, __shfl_xor(cmxA, 32, 64));
        cmxB = fmaxf(cmxB, __shfl_xor(cmxB, 32, 64));

        const float mnewA = fmaxf(mrunA, cmxA);
        const float mnewB = fmaxf(mrunB, cmxB);
        const float scaleA = __expf((mrunA - mnewA) * 0.125f);  // 0 on first chunk
        const float scaleB = __expf((mrunB - mnewB) * 0.125f);
        sumA *= scaleA;
        sumB *= scaleB;
#pragma unroll
        for (int i = 0; i < 4; ++i)
#pragma unroll
          for (int r = 0; r < 4; ++r) {
            oA[i][r] *= scaleA;
            oB[i][r] *= scaleB;
          }
        const float offsA = -mnewA * 0.125f;
        const float offsB = -mnewB * 0.125f;
        mrunA = mnewA;
        mrunB = mnewB;

        // exp -> pack -> PV (2 sub-chunks of 32 positions); V-frag shared A/B
#pragma unroll
        for (int kp = 0; kp < 2; ++kp) {
          float pA[8], pB[8];
#pragma unroll
          for (int h = 0; h < 2; ++h) {
            const int k8 = kp * 2 + h;
#pragma unroll
            for (int r = 0; r < 4; ++r) {
              pA[h * 4 + r] = __expf(fmaf(sA[k8][r], 0.125f, offsA));
              pB[h * 4 + r] = __expf(fmaf(sB[k8][r], 0.125f, offsB));
            }
          }
          sumA += ((pA[0] + pA[4]) + (pA[1] + pA[5])) + ((pA[2] + pA[6]) + (pA[3] + pA[7]));
          sumB += ((pB[0] + pB[4]) + (pB[1] + pB[5])) + ((pB[2] + pB[6]) + (pB[3] + pB[7]));
          short8 pfA, pfB;  // slot j -> pos = kpg*32 + (j>>2)*16 + quad*4 + (j&3)
#pragma unroll
          for (int j = 0; j < 8; ++j) {
            pfA[j] = (short)f2bf(pA[j]);
            pfB[j] = (short)f2bf(pB[j]);
          }
          const int kpg = ch * 2 + kp;
#pragma unroll
          for (int nto = 0; nto < 4; ++nto) {
            const int vb = (nto * 16 + ln) * 512 + quad * 128;
            const short8 vf = *reinterpret_cast<const short8*>(
                Vsw + vb + (((kpg << 3) ^ vxor)));
            oA[nto] = MFMA16(vf, pfA, oA[nto]);  // O^T[d=nto*16+quad*4+r][q=ln]
            oB[nto] = MFMA16(vf, pfB, oB[nto]);
          }
        }
      }

      sumA += __shfl_xor(sumA, 16, 64);
      sumB += __shfl_xor(sumB, 16, 64);
      sumA += __shfl_xor(sumA, 32, 64);
      sumB += __shfl_xor(sumB, 32, 64);
      const float invA = 1.0f / sumA;
      const float invB = 1.0f / sumB;

      // O^T -> bf16 B-frags
      short8 of0A, of1A, of0B, of1B;
#pragma unroll
      for (int r = 0; r < 4; ++r) {
        of0A[r] = (short)f2bf(oA[0][r] * invA);
        of0A[4 + r] = (short)f2bf(oA[1][r] * invA);
        of1A[r] = (short)f2bf(oA[2][r] * invA);
        of1A[4 + r] = (short)f2bf(oA[3][r] * invA);
        of0B[r] = (short)f2bf(oB[0][r] * invB);
        of0B[4 + r] = (short)f2bf(oB[1][r] * invB);
        of1B[r] = (short)f2bf(oB[2][r] * invB);
        of1B[4 + r] = (short)f2bf(oB[3][r] * invB);
      }

      // dense: Z^T = Wd^T @ O^T; Wd frags shared A/B; float4 epilogue
#pragma unroll
      for (int nt = 0; nt < 4; ++nt) {
        const int ebase = (nt * 16 + ln) * 64;
        const short8 w0 = *reinterpret_cast<const short8*>(
            Wdsw + ebase + ((quad ^ e8) << 3));
        const short8 w1 = *reinterpret_cast<const short8*>(
            Wdsw + ebase + (((4 + quad) ^ e8) << 3));
        float4v accA = {0.f, 0.f, 0.f, 0.f};
        accA = MFMA16(w0, of0A, accA);
        accA = MFMA16(w1, of1A, accA);
        float4v accB = {0.f, 0.f, 0.f, 0.f};
        accB = MFMA16(w0, of0B, accB);
        accB = MFMA16(w1, of1B, accB);
        const int e0 = nt * 16 + quad * 4;  // channel base (4 consecutive)
#pragma unroll
        for (int t = 0; t < 2; ++t) {
          const int row = (t == 0 ? qtA : qtB) * 16 + ln;
          const float4v acc = t == 0 ? accA : accB;
          float4v* op = reinterpret_cast<float4v*>(outb + row * 64 + e0);
          if (br == 0) {
            *op = acc;  // park temporal branch (sans bias)
          } else {
            // bias loaded here (L1-hot broadcast) instead of held in regs
            const float4v bt = *reinterpret_cast<const float4v*>(bd_t + e0);
            const float4v bs = *reinterpret_cast<const float4v*>(bd_s + e0);
            const float4v parked = *op;
            const float4v xv = *reinterpret_cast<const float4v*>(xb + row * 64 + e0);
            float4v res;
#pragma unroll
            for (int r = 0; r < 4; ++r) {
              const float z = parked[r] + acc[r] + bt[r] + bs[r];
              const float gate = 1.0f / (1.0f + __expf(-z));
              res[r] = xv[r] * gate;
            }
            *op = res;
          }
        }
      }
    }
    __syncthreads();  // protect K/V/W LDS before next branch restages
  }
}

extern "C" void kernel_launch(void* const* d_in, const int* in_sizes, int n_in,
                              void* d_out, int out_size, void* d_ws, size_t ws_size,
                              hipStream_t stream) {
  const float* x = (const float*)d_in[0];
  const float* Wq_t = (const float*)d_in[1];
  const float* Wk_t = (const float*)d_in[2];
  const float* Wv_t = (const float*)d_in[3];
  const float* Wq_s = (const float*)d_in[4];
  const float* Wk_s = (const float*)d_in[5];
  const float* Wv_s = (const float*)d_in[6];
  const float* Wd_t = (const float*)d_in[7];
  const float* bd_t = (const float*)d_in[8];
  const float* Wd_s = (const float*)d_in[9];
  const float* bd_s = (const float*)d_in[10];
  float* out = (float*)d_out;
  unsigned short* qws = (unsigned short*)d_ws;  // 256*512*64*2 = 16 MiB

  hipFuncSetAttribute(reinterpret_cast<const void*>(ts_attn_fused),
                      hipFuncAttributeMaxDynamicSharedMemorySize, LDS_TOTAL_BYTES);
  ts_attn_fused<<<dim3(256), dim3(kThreads), LDS_TOTAL_BYTES, stream>>>(
      x, Wq_t, Wk_t, Wv_t, Wq_s, Wk_s, Wv_s, Wd_t, bd_t, Wd_s, bd_s, out, qws);
}

// Round 12
// 275.182 us; speedup vs baseline: 1.0131x; 1.0131x over previous
//
#include <hip/hip_runtime.h>

typedef __attribute__((ext_vector_type(8))) short short8;
typedef __attribute__((ext_vector_type(4))) short short4v;
typedef __attribute__((ext_vector_type(4))) float float4v;

#define MFMA16(a, b, c) __builtin_amdgcn_mfma_f32_16x16x32_bf16((a), (b), (c), 0, 0, 0)

constexpr int kThreads = 1024;  // 16 waves -> 4 waves/SIMD at 1 block/CU
// LDS (ushort units):
//   [0,     32768)  K2 : pos-major; 8 granules of 16B per pos-row.
//                   granule g = cp*4+quad (XOR pos&7); content
//                   [K[pos][cp*32+quad*4+0..3], K[pos][cp*32+16+quad*4+0..3]]
//   [32768, 65536)  V2 : d-major; granule [qg][kp] with kp-field XOR (d&7) XOR qg;
//                   content [V[kp*32+qg*4+0..3][d], V[kp*32+16+qg*4+0..3][d]]
//   [65536, 77824)  Wq^T/Wk^T/Wv^T staging (3 x 4096), 8-consecutive-d b128 frags
//   [77824, 81920)  Wd2 : e-major; granule g = cp*4+quad (XOR e&7)
constexpr int LDS_TOTAL_BYTES = 163840;  // 160 KiB -> 1 block/CU
// OCCUPANCY/REGISTER PIN (r10/r11 lesson): __launch_bounds__' 2nd arg lowers
// to a waves-per-eu MINIMUM only; the allocator still TARGETS max occupancy
// (8/EU, since dynamic LDS is invisible at compile time) -> 64-VGPR budget ->
// ~1.45 KB/thread scratch (hbm 1.9e8 -> 5.7e8 B). Both (1024,4) and (1024)
// builds hit this. amdgpu_waves_per_eu(4,4) pins the range from BOTH sides:
// budget = 512/4 = 128 VGPR, which the phase-2 body (r8-proven) fits cleanly.

static __device__ __forceinline__ unsigned short f2bf(float f) {
  // native cast -> HW v_cvt_pk_bf16_f32 (RNE)
  __bf16 h = (__bf16)f;
  return __builtin_bit_cast(unsigned short, h);
}

// W^T staging swizzle for phase 1 (b128 frags of 8 consecutive d).
static __device__ __forceinline__ int wsw_idx(int e, int d) {
  return ((((d >> 3) << 9) + (e << 3) + (d & 7)) ^ (((d >> 3) & 3) << 3));
}

__global__ __launch_bounds__(kThreads)
__attribute__((amdgpu_waves_per_eu(4, 4)))
void ts_attn_fused(
    const float* __restrict__ x, const float* __restrict__ Wq_t,
    const float* __restrict__ Wk_t, const float* __restrict__ Wv_t,
    const float* __restrict__ Wq_s, const float* __restrict__ Wk_s,
    const float* __restrict__ Wv_s, const float* __restrict__ Wd_t,
    const float* __restrict__ bd_t, const float* __restrict__ Wd_s,
    const float* __restrict__ bd_s, float* __restrict__ out,
    unsigned short* __restrict__ qws) {
  extern __shared__ __align__(16) unsigned short smem[];
  unsigned short* Ksw = smem;            // 32768 us
  unsigned short* Vsw = smem + 32768;    // 32768 us
  unsigned short* Wst = smem + 65536;    // 12288 us (3 x 4096)
  unsigned short* Wdsw = smem + 77824;   // 4096 us

  const int tid = threadIdx.x;
  const int wv = tid >> 6;    // wave 0..15
  const int lane = tid & 63;
  const int ln = lane & 15;   // q position within 16-tile
  const int quad = lane >> 4;
  const int e8 = ln & 7;      // lane-constant XOR key (pos&7 / e&7 of this lane's rows)
  const int b = blockIdx.x;

  const float* xb = x + (size_t)b * (512 * 64);
  float* outb = out + (size_t)b * (512 * 64);
  unsigned short* qg = qws + (size_t)b * (512 * 64);  // Q bf16 in slot-group order

#pragma unroll 1
  for (int br = 0; br < 2; ++br) {
    const float* Wq = br ? Wq_s : Wq_t;
    const float* Wk = br ? Wk_s : Wk_t;
    const float* Wv = br ? Wv_s : Wv_t;
    const float* Wd = br ? Wd_s : Wd_t;

    // ---- stage weight matrices into LDS (bf16); 4 elems/thread ----
    {
      const int d = tid >> 4;        // 0..63
      const int e0 = (tid & 15) * 4; // 0..60
      const float* srcs[3] = {Wq, Wk, Wv};
#pragma unroll
      for (int g = 0; g < 3; ++g) {
        const float4v u = *reinterpret_cast<const float4v*>(srcs[g] + d * 64 + e0);
        unsigned short* dst = Wst + g * 4096;
#pragma unroll
        for (int i = 0; i < 4; ++i) dst[wsw_idx(e0 + i, d)] = f2bf(u[i]);
      }
      // Wd -> Wd2 slot-group layout: d -> (cp, quad_g, h)
      const int cp_ = d >> 5;
      const int c = d & 31;
      const int qd_ = (c >> 2) & 3;
      const int h_ = ((c >> 4) << 2) | (c & 3);
      const int gbase = (cp_ * 4 + qd_);
      const float4v u = *reinterpret_cast<const float4v*>(Wd + d * 64 + e0);
#pragma unroll
      for (int i = 0; i < 4; ++i) {
        const int e = e0 + i;
        Wdsw[e * 64 + ((gbase ^ (e & 7)) << 3) + h_] = f2bf(u[i]);
      }
    }
    __syncthreads();

    // ---- phase 1: Q^T,K^T,V^T = W^T @ X^T. Q -> global ws; K,V -> LDS ----
#pragma unroll 1
    for (int mi = 0; mi < 2; ++mi) {
      const int mrow = (wv + mi * 16) * 16 + ln;
      // V2 decomposition of this row's position (for g==2 writes)
      const int kpq = mrow >> 5;
      const int w5 = mrow & 31;
      const int jj = ((w5 >> 4) << 2) | (w5 & 3);
      const int qg2 = (w5 >> 2) & 3;
      short8 xa0, xa1;  // X^T B-frags (native 8-run: slot j -> d = cc*32 + quad*8 + j)
      {
        const float4v u0 = *reinterpret_cast<const float4v*>(xb + mrow * 64 + quad * 8);
        const float4v v0 = *reinterpret_cast<const float4v*>(xb + mrow * 64 + quad * 8 + 4);
        const float4v u1 = *reinterpret_cast<const float4v*>(xb + mrow * 64 + 32 + quad * 8);
        const float4v v1 = *reinterpret_cast<const float4v*>(xb + mrow * 64 + 32 + quad * 8 + 4);
#pragma unroll
        for (int i = 0; i < 4; ++i) {
          xa0[i] = (short)f2bf(u0[i]);
          xa0[4 + i] = (short)f2bf(v0[i]);
          xa1[i] = (short)f2bf(u1[i]);
          xa1[4 + i] = (short)f2bf(v1[i]);
        }
      }
#pragma unroll
      for (int g = 0; g < 3; ++g) {
        const unsigned short* Wg = Wst + g * 4096;
#pragma unroll
        for (int nt = 0; nt < 4; ++nt) {
          const short8 w0 = *reinterpret_cast<const short8*>(Wg + wsw_idx(nt * 16 + ln, quad * 8));
          const short8 w1 = *reinterpret_cast<const short8*>(Wg + wsw_idx(nt * 16 + ln, 32 + quad * 8));
          float4v acc = {0.f, 0.f, 0.f, 0.f};
          acc = MFMA16(w0, xa0, acc);
          acc = MFMA16(w1, xa1, acc);
          // D-frag: acc[r] = M[mrow][e = nt*16 + quad*4 + r]
          if (g == 0) {
            short4v pk;
#pragma unroll
            for (int r = 0; r < 4; ++r) pk[r] = (short)f2bf(acc[r]);
            *reinterpret_cast<short4v*>(
                qg + mrow * 64 + (nt >> 1) * 32 + quad * 8 + (nt & 1) * 4) = pk;
          } else if (g == 1) {
            short4v pk;
#pragma unroll
            for (int r = 0; r < 4; ++r) pk[r] = (short)f2bf(acc[r]);
            const int gswz = ((nt >> 1) * 4 + quad) ^ (mrow & 7);
            *reinterpret_cast<short4v*>(
                Ksw + mrow * 64 + (gswz << 3) + (nt & 1) * 4) = pk;
          } else {
            // V write: granule field XOR qg2 spreads the 16-lane store across
            // 4 bank-groups (was 8-way conflict in 2 banks without it).
#pragma unroll
            for (int r = 0; r < 4; ++r) {
              const int d = nt * 16 + quad * 4 + r;
              const int gv = (kpq ^ (d & 7) ^ qg2);
              Vsw[(d << 9) + (qg2 << 7) + (gv << 3) + jj] = f2bf(acc[r]);
            }
          }
        }
      }
    }
    __syncthreads();

    // ---- phase 2: each wave owns q-tile pair (A: wv, B: wv+16) ----
    // K/V/Wd ds_reads feed both tiles; dual softmax chains give ILP.
    // Online softmax window = 4 K-tiles (64 pos) -> sA[4]+sB[4] = 32 live regs.
    {
      const int qtA = wv;
      const int qtB = wv + 16;
      const unsigned short* qrowA = qg + (qtA * 16 + ln) * 64;
      const unsigned short* qrowB = qg + (qtB * 16 + ln) * 64;
      const short8 qaA = *reinterpret_cast<const short8*>(qrowA + quad * 8);
      const short8 qbA = *reinterpret_cast<const short8*>(qrowA + 32 + quad * 8);
      const short8 qaB = *reinterpret_cast<const short8*>(qrowB + quad * 8);
      const short8 qbB = *reinterpret_cast<const short8*>(qrowB + 32 + quad * 8);

      const int kb0 = ln * 64 + ((quad ^ e8) << 3);        // cp=0 granule
      const int kb1 = ln * 64 + (((4 + quad) ^ e8) << 3);  // cp=1 granule
      const int vxor = (quad << 3) ^ (e8 << 3);            // V read granule XOR

      float4v oA[4], oB[4];
#pragma unroll
      for (int i = 0; i < 4; ++i) {
        oA[i] = (float4v){0.f, 0.f, 0.f, 0.f};
        oB[i] = (float4v){0.f, 0.f, 0.f, 0.f};
      }
      float mrunA = -3.0e38f, mrunB = -3.0e38f;
      float sumA = 0.f, sumB = 0.f;

#pragma unroll 1
      for (int ch = 0; ch < 8; ++ch) {
        // S chunks for both tiles: s*[k8][r], pos = (ch*4+k8)*16 + quad*4 + r
        float4v sA[4], sB[4];
#pragma unroll
        for (int k8 = 0; k8 < 4; ++k8) {
          const int kt = ch * 4 + k8;
          const short8 k0 = *reinterpret_cast<const short8*>(Ksw + kt * 1024 + kb0);
          const short8 k1 = *reinterpret_cast<const short8*>(Ksw + kt * 1024 + kb1);
          float4v aA = {0.f, 0.f, 0.f, 0.f};
          aA = MFMA16(k0, qaA, aA);
          aA = MFMA16(k1, qbA, aA);
          sA[k8] = aA;
          float4v aB = {0.f, 0.f, 0.f, 0.f};
          aB = MFMA16(k0, qaB, aB);
          aB = MFMA16(k1, qbB, aB);
          sB[k8] = aB;
        }

        // chunk max per tile (independent serial chains -> good dual issue)
        float4v m4A = sA[0], m4B = sB[0];
#pragma unroll
        for (int k8 = 1; k8 < 4; ++k8)
#pragma unroll
          for (int r = 0; r < 4; ++r) {
            m4A[r] = fmaxf(m4A[r], sA[k8][r]);
            m4B[r] = fmaxf(m4B[r], sB[k8][r]);
          }
        float cmxA = fmaxf(fmaxf(m4A[0], m4A[1]), fmaxf(m4A[2], m4A[3]));
        float cmxB = fmaxf(fmaxf(m4B[0], m4B[1]), fmaxf(m4B[2], m4B[3]));
        cmxA = fmaxf(cmxA, __shfl_xor(cmxA, 16, 64));
        cmxB = fmaxf(cmxB, __shfl_xor(cmxB, 16, 64));
        cmxA = fmaxf(cmxA, __shfl_xor(cmxA, 32, 64));
        cmxB = fmaxf(cmxB, __shfl_xor(cmxB, 32, 64));

        const float mnewA = fmaxf(mrunA, cmxA);
        const float mnewB = fmaxf(mrunB, cmxB);
        const float scaleA = __expf((mrunA - mnewA) * 0.125f);  // 0 on first chunk
        const float scaleB = __expf((mrunB - mnewB) * 0.125f);
        sumA *= scaleA;
        sumB *= scaleB;
#pragma unroll
        for (int i = 0; i < 4; ++i)
#pragma unroll
          for (int r = 0; r < 4; ++r) {
            oA[i][r] *= scaleA;
            oB[i][r] *= scaleB;
          }
        const float offsA = -mnewA * 0.125f;
        const float offsB = -mnewB * 0.125f;
        mrunA = mnewA;
        mrunB = mnewB;

        // exp -> pack -> PV (2 sub-chunks of 32 positions); V-frag shared A/B
#pragma unroll
        for (int kp = 0; kp < 2; ++kp) {
          float pA[8], pB[8];
#pragma unroll
          for (int h = 0; h < 2; ++h) {
            const int k8 = kp * 2 + h;
#pragma unroll
            for (int r = 0; r < 4; ++r) {
              pA[h * 4 + r] = __expf(fmaf(sA[k8][r], 0.125f, offsA));
              pB[h * 4 + r] = __expf(fmaf(sB[k8][r], 0.125f, offsB));
            }
          }
          sumA += ((pA[0] + pA[4]) + (pA[1] + pA[5])) + ((pA[2] + pA[6]) + (pA[3] + pA[7]));
          sumB += ((pB[0] + pB[4]) + (pB[1] + pB[5])) + ((pB[2] + pB[6]) + (pB[3] + pB[7]));
          short8 pfA, pfB;  // slot j -> pos = kpg*32 + (j>>2)*16 + quad*4 + (j&3)
#pragma unroll
          for (int j = 0; j < 8; ++j) {
            pfA[j] = (short)f2bf(pA[j]);
            pfB[j] = (short)f2bf(pB[j]);
          }
          const int kpg = ch * 2 + kp;
#pragma unroll
          for (int nto = 0; nto < 4; ++nto) {
            const int vb = (nto * 16 + ln) * 512 + quad * 128;
            const short8 vf = *reinterpret_cast<const short8*>(
                Vsw + vb + (((kpg << 3) ^ vxor)));
            oA[nto] = MFMA16(vf, pfA, oA[nto]);  // O^T[d=nto*16+quad*4+r][q=ln]
            oB[nto] = MFMA16(vf, pfB, oB[nto]);
          }
        }
      }

      sumA += __shfl_xor(sumA, 16, 64);
      sumB += __shfl_xor(sumB, 16, 64);
      sumA += __shfl_xor(sumA, 32, 64);
      sumB += __shfl_xor(sumB, 32, 64);
      const float invA = 1.0f / sumA;
      const float invB = 1.0f / sumB;

      // O^T -> bf16 B-frags
      short8 of0A, of1A, of0B, of1B;
#pragma unroll
      for (int r = 0; r < 4; ++r) {
        of0A[r] = (short)f2bf(oA[0][r] * invA);
        of0A[4 + r] = (short)f2bf(oA[1][r] * invA);
        of1A[r] = (short)f2bf(oA[2][r] * invA);
        of1A[4 + r] = (short)f2bf(oA[3][r] * invA);
        of0B[r] = (short)f2bf(oB[0][r] * invB);
        of0B[4 + r] = (short)f2bf(oB[1][r] * invB);
        of1B[r] = (short)f2bf(oB[2][r] * invB);
        of1B[4 + r] = (short)f2bf(oB[3][r] * invB);
      }

      // dense: Z^T = Wd^T @ O^T; Wd frags shared A/B; float4 epilogue
#pragma unroll
      for (int nt = 0; nt < 4; ++nt) {
        const int ebase = (nt * 16 + ln) * 64;
        const short8 w0 = *reinterpret_cast<const short8*>(
            Wdsw + ebase + ((quad ^ e8) << 3));
        const short8 w1 = *reinterpret_cast<const short8*>(
            Wdsw + ebase + (((4 + quad) ^ e8) << 3));
        float4v accA = {0.f, 0.f, 0.f, 0.f};
        accA = MFMA16(w0, of0A, accA);
        accA = MFMA16(w1, of1A, accA);
        float4v accB = {0.f, 0.f, 0.f, 0.f};
        accB = MFMA16(w0, of0B, accB);
        accB = MFMA16(w1, of1B, accB);
        const int e0 = nt * 16 + quad * 4;  // channel base (4 consecutive)
#pragma unroll
        for (int t = 0; t < 2; ++t) {
          const int row = (t == 0 ? qtA : qtB) * 16 + ln;
          const float4v acc = t == 0 ? accA : accB;
          float4v* op = reinterpret_cast<float4v*>(outb + row * 64 + e0);
          if (br == 0) {
            *op = acc;  // park temporal branch (sans bias)
          } else {
            // bias loaded here (L1-hot broadcast) instead of held in regs
            const float4v bt = *reinterpret_cast<const float4v*>(bd_t + e0);
            const float4v bs = *reinterpret_cast<const float4v*>(bd_s + e0);
            const float4v parked = *op;
            const float4v xv = *reinterpret_cast<const float4v*>(xb + row * 64 + e0);
            float4v res;
#pragma unroll
            for (int r = 0; r < 4; ++r) {
              const float z = parked[r] + acc[r] + bt[r] + bs[r];
              const float gate = 1.0f / (1.0f + __expf(-z));
              res[r] = xv[r] * gate;
            }
            *op = res;
          }
        }
      }
    }
    __syncthreads();  // protect K/V/W LDS before next branch restages
  }
}

extern "C" void kernel_launch(void* const* d_in, const int* in_sizes, int n_in,
                              void* d_out, int out_size, void* d_ws, size_t ws_size,
                              hipStream_t stream) {
  const float* x = (const float*)d_in[0];
  const float* Wq_t = (const float*)d_in[1];
  const float* Wk_t = (const float*)d_in[2];
  const float* Wv_t = (const float*)d_in[3];
  const float* Wq_s = (const float*)d_in[4];
  const float* Wk_s = (const float*)d_in[5];
  const float* Wv_s = (const float*)d_in[6];
  const float* Wd_t = (const float*)d_in[7];
  const float* bd_t = (const float*)d_in[8];
  const float* Wd_s = (const float*)d_in[9];
  const float* bd_s = (const float*)d_in[10];
  float* out = (float*)d_out;
  unsigned short* qws = (unsigned short*)d_ws;  // 256*512*64*2 = 16 MiB

  hipFuncSetAttribute(reinterpret_cast<const void*>(ts_attn_fused),
                      hipFuncAttributeMaxDynamicSharedMemorySize, LDS_TOTAL_BYTES);
  ts_attn_fused<<<dim3(256), dim3(kThreads), LDS_TOTAL_BYTES, stream>>>(
      x, Wq_t, Wk_t, Wv_t, Wq_s, Wk_s, Wv_s, Wd_t, bd_t, Wd_s, bd_s, out, qws);
}

// Round 13
// 236.946 us; speedup vs baseline: 1.1766x; 1.1614x over previous
//
#include <hip/hip_runtime.h>

typedef __attribute__((ext_vector_type(8))) short short8;
typedef __attribute__((ext_vector_type(4))) short short4v;
typedef __attribute__((ext_vector_type(4))) float float4v;

#define MFMA16(a, b, c) __builtin_amdgcn_mfma_f32_16x16x32_bf16((a), (b), (c), 0, 0, 0)

constexpr int kThreads = 1024;  // 16 waves -> 4 waves/SIMD at 1 block/CU
// LDS (ushort units):
//   [0,     32768)  K2 : pos-major; 8 granules of 16B per pos-row.
//                   granule g = cp*4+quad (XOR pos&7); content
//                   [K[pos][cp*32+quad*4+0..3], K[pos][cp*32+16+quad*4+0..3]]
//   [32768, 65536)  V2 : d-major; granule [qg][kp] with kp-field XOR (d&7) XOR qg;
//                   content [V[kp*32+qg*4+0..3][d], V[kp*32+16+qg*4+0..3][d]]
//   [65536, 77824)  Wq^T/Wk^T/Wv^T staging (3 x 4096), 8-consecutive-d b128 frags
//   [77824, 81920)  Wd2 : e-major; granule g = cp*4+quad (XOR e&7)
constexpr int LDS_TOTAL_BYTES = 163840;  // 160 KiB -> 1 block/CU
// REGISTER REALITY (r10/r11/r12, three controlled failures): a 1024-thread
// workgroup gets a 64-arch-VGPR budget on this toolchain. __launch_bounds__
// 2nd arg, no 2nd arg, and amdgpu_waves_per_eu(4,4) all leave VGPR=64 and
// spill if demand exceeds it. Therefore: DESIGN FOR 64 ARCH VGPRS.
// Phase 2 here is single-q-tile (peak live ~60): s[4]=16 + o[4]=16 + Q 8 +
// p/pf 12 + addressing. The 2-tile variant (~130 live) is what spilled.

static __device__ __forceinline__ unsigned short f2bf(float f) {
  // native cast -> HW v_cvt_pk_bf16_f32 (RNE)
  __bf16 h = (__bf16)f;
  return __builtin_bit_cast(unsigned short, h);
}

// W^T staging swizzle for phase 1 (b128 frags of 8 consecutive d).
static __device__ __forceinline__ int wsw_idx(int e, int d) {
  return ((((d >> 3) << 9) + (e << 3) + (d & 7)) ^ (((d >> 3) & 3) << 3));
}

__global__ __launch_bounds__(kThreads) void ts_attn_fused(
    const float* __restrict__ x, const float* __restrict__ Wq_t,
    const float* __restrict__ Wk_t, const float* __restrict__ Wv_t,
    const float* __restrict__ Wq_s, const float* __restrict__ Wk_s,
    const float* __restrict__ Wv_s, const float* __restrict__ Wd_t,
    const float* __restrict__ bd_t, const float* __restrict__ Wd_s,
    const float* __restrict__ bd_s, float* __restrict__ out,
    unsigned short* __restrict__ qws) {
  extern __shared__ __align__(16) unsigned short smem[];
  unsigned short* Ksw = smem;            // 32768 us
  unsigned short* Vsw = smem + 32768;    // 32768 us
  unsigned short* Wst = smem + 65536;    // 12288 us (3 x 4096)
  unsigned short* Wdsw = smem + 77824;   // 4096 us

  const int tid = threadIdx.x;
  const int wv = tid >> 6;    // wave 0..15
  const int lane = tid & 63;
  const int ln = lane & 15;   // q position within 16-tile
  const int quad = lane >> 4;
  const int e8 = ln & 7;      // lane-constant XOR key (pos&7 / e&7 of this lane's rows)
  const int b = blockIdx.x;

  const float* xb = x + (size_t)b * (512 * 64);
  float* outb = out + (size_t)b * (512 * 64);
  unsigned short* qg = qws + (size_t)b * (512 * 64);  // Q bf16 in slot-group order

#pragma unroll 1
  for (int br = 0; br < 2; ++br) {
    const float* Wq = br ? Wq_s : Wq_t;
    const float* Wk = br ? Wk_s : Wk_t;
    const float* Wv = br ? Wv_s : Wv_t;
    const float* Wd = br ? Wd_s : Wd_t;

    // ---- stage weight matrices into LDS (bf16); 4 elems/thread ----
    {
      const int d = tid >> 4;        // 0..63
      const int e0 = (tid & 15) * 4; // 0..60
      const float* srcs[3] = {Wq, Wk, Wv};
#pragma unroll
      for (int g = 0; g < 3; ++g) {
        const float4v u = *reinterpret_cast<const float4v*>(srcs[g] + d * 64 + e0);
        unsigned short* dst = Wst + g * 4096;
#pragma unroll
        for (int i = 0; i < 4; ++i) dst[wsw_idx(e0 + i, d)] = f2bf(u[i]);
      }
      // Wd -> Wd2 slot-group layout: d -> (cp, quad_g, h)
      const int cp_ = d >> 5;
      const int c = d & 31;
      const int qd_ = (c >> 2) & 3;
      const int h_ = ((c >> 4) << 2) | (c & 3);
      const int gbase = (cp_ * 4 + qd_);
      const float4v u = *reinterpret_cast<const float4v*>(Wd + d * 64 + e0);
#pragma unroll
      for (int i = 0; i < 4; ++i) {
        const int e = e0 + i;
        Wdsw[e * 64 + ((gbase ^ (e & 7)) << 3) + h_] = f2bf(u[i]);
      }
    }
    __syncthreads();

    // ---- phase 1: Q^T,K^T,V^T = W^T @ X^T. Q -> global ws; K,V -> LDS ----
#pragma unroll 1
    for (int mi = 0; mi < 2; ++mi) {
      const int mrow = (wv + mi * 16) * 16 + ln;
      // V2 decomposition of this row's position (for g==2 writes)
      const int kpq = mrow >> 5;
      const int w5 = mrow & 31;
      const int jj = ((w5 >> 4) << 2) | (w5 & 3);
      const int qg2 = (w5 >> 2) & 3;
      short8 xa0, xa1;  // X^T B-frags (native 8-run: slot j -> d = cc*32 + quad*8 + j)
      {
        const float4v u0 = *reinterpret_cast<const float4v*>(xb + mrow * 64 + quad * 8);
        const float4v v0 = *reinterpret_cast<const float4v*>(xb + mrow * 64 + quad * 8 + 4);
        const float4v u1 = *reinterpret_cast<const float4v*>(xb + mrow * 64 + 32 + quad * 8);
        const float4v v1 = *reinterpret_cast<const float4v*>(xb + mrow * 64 + 32 + quad * 8 + 4);
#pragma unroll
        for (int i = 0; i < 4; ++i) {
          xa0[i] = (short)f2bf(u0[i]);
          xa0[4 + i] = (short)f2bf(v0[i]);
          xa1[i] = (short)f2bf(u1[i]);
          xa1[4 + i] = (short)f2bf(v1[i]);
        }
      }
#pragma unroll
      for (int g = 0; g < 3; ++g) {
        const unsigned short* Wg = Wst + g * 4096;
#pragma unroll
        for (int nt = 0; nt < 4; ++nt) {
          const short8 w0 = *reinterpret_cast<const short8*>(Wg + wsw_idx(nt * 16 + ln, quad * 8));
          const short8 w1 = *reinterpret_cast<const short8*>(Wg + wsw_idx(nt * 16 + ln, 32 + quad * 8));
          float4v acc = {0.f, 0.f, 0.f, 0.f};
          acc = MFMA16(w0, xa0, acc);
          acc = MFMA16(w1, xa1, acc);
          // D-frag: acc[r] = M[mrow][e = nt*16 + quad*4 + r]
          if (g == 0) {
            short4v pk;
#pragma unroll
            for (int r = 0; r < 4; ++r) pk[r] = (short)f2bf(acc[r]);
            *reinterpret_cast<short4v*>(
                qg + mrow * 64 + (nt >> 1) * 32 + quad * 8 + (nt & 1) * 4) = pk;
          } else if (g == 1) {
            short4v pk;
#pragma unroll
            for (int r = 0; r < 4; ++r) pk[r] = (short)f2bf(acc[r]);
            const int gswz = ((nt >> 1) * 4 + quad) ^ (mrow & 7);
            *reinterpret_cast<short4v*>(
                Ksw + mrow * 64 + (gswz << 3) + (nt & 1) * 4) = pk;
          } else {
            // V write: granule field XOR qg2 spreads the 16-lane store across
            // 4 bank-groups (was 8-way conflict in 2 banks without it).
#pragma unroll
            for (int r = 0; r < 4; ++r) {
              const int d = nt * 16 + quad * 4 + r;
              const int gv = (kpq ^ (d & 7) ^ qg2);
              Vsw[(d << 9) + (qg2 << 7) + (gv << 3) + jj] = f2bf(acc[r]);
            }
          }
        }
      }
    }
    __syncthreads();

    // ---- phase 2: ONE q-tile per iteration (qt = wv + qi*16), 16 waves ----
    // Single-tile body keeps peak live ~60 regs -> fits the 64-VGPR budget;
    // 4 waves/SIMD provides the latency hiding the 2-wave r8 build lacked.
    {
      const int kb0 = ln * 64 + ((quad ^ e8) << 3);        // cp=0 granule
      const int kb1 = ln * 64 + (((4 + quad) ^ e8) << 3);  // cp=1 granule
      const int vxor = (quad << 3) ^ (e8 << 3);            // V read granule XOR

#pragma unroll 1
      for (int qi = 0; qi < 2; ++qi) {
        const int qt = wv + qi * 16;
        const unsigned short* qrow = qg + (qt * 16 + ln) * 64;
        const short8 qa = *reinterpret_cast<const short8*>(qrow + quad * 8);
        const short8 qb = *reinterpret_cast<const short8*>(qrow + 32 + quad * 8);

        float4v o[4];
#pragma unroll
        for (int i = 0; i < 4; ++i) o[i] = (float4v){0.f, 0.f, 0.f, 0.f};
        float mrun = -3.0e38f;
        float sum = 0.f;

#pragma unroll 1
        for (int ch = 0; ch < 8; ++ch) {
          // S chunk: s[k8][r], pos = (ch*4+k8)*16 + quad*4 + r, q = qt*16 + ln
          float4v s[4];
#pragma unroll
          for (int k8 = 0; k8 < 4; ++k8) {
            const int kt = ch * 4 + k8;
            const short8 k0 = *reinterpret_cast<const short8*>(Ksw + kt * 1024 + kb0);
            const short8 k1 = *reinterpret_cast<const short8*>(Ksw + kt * 1024 + kb1);
            float4v a = {0.f, 0.f, 0.f, 0.f};
            a = MFMA16(k0, qa, a);
            a = MFMA16(k1, qb, a);
            s[k8] = a;
          }

          // chunk max, then cross-quad reduce
          float4v m4 = s[0];
#pragma unroll
          for (int k8 = 1; k8 < 4; ++k8)
#pragma unroll
            for (int r = 0; r < 4; ++r) m4[r] = fmaxf(m4[r], s[k8][r]);
          float cmx = fmaxf(fmaxf(m4[0], m4[1]), fmaxf(m4[2], m4[3]));
          cmx = fmaxf(cmx, __shfl_xor(cmx, 16, 64));
          cmx = fmaxf(cmx, __shfl_xor(cmx, 32, 64));

          const float mnew = fmaxf(mrun, cmx);
          const float scale = __expf((mrun - mnew) * 0.125f);  // 0 on first chunk
          sum *= scale;
#pragma unroll
          for (int i = 0; i < 4; ++i)
#pragma unroll
            for (int r = 0; r < 4; ++r) o[i][r] *= scale;
          const float offs = -mnew * 0.125f;
          mrun = mnew;

          // exp -> pack -> PV (2 sub-chunks of 32 positions)
#pragma unroll
          for (int kp = 0; kp < 2; ++kp) {
            float p[8];
#pragma unroll
            for (int h = 0; h < 2; ++h) {
              const int k8 = kp * 2 + h;
#pragma unroll
              for (int r = 0; r < 4; ++r)
                p[h * 4 + r] = __expf(fmaf(s[k8][r], 0.125f, offs));
            }
            sum += ((p[0] + p[4]) + (p[1] + p[5])) + ((p[2] + p[6]) + (p[3] + p[7]));
            short8 pf;  // slot j -> pos = kpg*32 + (j>>2)*16 + quad*4 + (j&3)
#pragma unroll
            for (int j = 0; j < 8; ++j) pf[j] = (short)f2bf(p[j]);
            const int kpg = ch * 2 + kp;
#pragma unroll
            for (int nto = 0; nto < 4; ++nto) {
              const int vb = (nto * 16 + ln) * 512 + quad * 128;
              const short8 vf = *reinterpret_cast<const short8*>(
                  Vsw + vb + (((kpg << 3) ^ vxor)));
              o[nto] = MFMA16(vf, pf, o[nto]);  // O^T[d=nto*16+quad*4+r][q=ln]
            }
          }
        }

        sum += __shfl_xor(sum, 16, 64);
        sum += __shfl_xor(sum, 32, 64);
        const float inv = 1.0f / sum;

        // O^T -> bf16 B-frags
        short8 of0, of1;
#pragma unroll
        for (int r = 0; r < 4; ++r) {
          of0[r] = (short)f2bf(o[0][r] * inv);
          of0[4 + r] = (short)f2bf(o[1][r] * inv);
          of1[r] = (short)f2bf(o[2][r] * inv);
          of1[4 + r] = (short)f2bf(o[3][r] * inv);
        }

        // dense: Z^T = Wd^T @ O^T; float4 epilogue
#pragma unroll
        for (int nt = 0; nt < 4; ++nt) {
          const int ebase = (nt * 16 + ln) * 64;
          const short8 w0 = *reinterpret_cast<const short8*>(
              Wdsw + ebase + ((quad ^ e8) << 3));
          const short8 w1 = *reinterpret_cast<const short8*>(
              Wdsw + ebase + (((4 + quad) ^ e8) << 3));
          float4v acc = {0.f, 0.f, 0.f, 0.f};
          acc = MFMA16(w0, of0, acc);
          acc = MFMA16(w1, of1, acc);
          const int row = qt * 16 + ln;       // position
          const int e0 = nt * 16 + quad * 4;  // channel base (4 consecutive)
          float4v* op = reinterpret_cast<float4v*>(outb + row * 64 + e0);
          if (br == 0) {
            *op = acc;  // park temporal branch (sans bias)
          } else {
            // bias loaded here (L1-hot broadcast) instead of held in regs
            const float4v bt = *reinterpret_cast<const float4v*>(bd_t + e0);
            const float4v bs = *reinterpret_cast<const float4v*>(bd_s + e0);
            const float4v parked = *op;
            const float4v xv = *reinterpret_cast<const float4v*>(xb + row * 64 + e0);
            float4v res;
#pragma unroll
            for (int r = 0; r < 4; ++r) {
              const float z = parked[r] + acc[r] + bt[r] + bs[r];
              const float gate = 1.0f / (1.0f + __expf(-z));
              res[r] = xv[r] * gate;
            }
            *op = res;
          }
        }
      }
    }
    __syncthreads();  // protect K/V/W LDS before next branch restages
  }
}

extern "C" void kernel_launch(void* const* d_in, const int* in_sizes, int n_in,
                              void* d_out, int out_size, void* d_ws, size_t ws_size,
                              hipStream_t stream) {
  const float* x = (const float*)d_in[0];
  const float* Wq_t = (const float*)d_in[1];
  const float* Wk_t = (const float*)d_in[2];
  const float* Wv_t = (const float*)d_in[3];
  const float* Wq_s = (const float*)d_in[4];
  const float* Wk_s = (const float*)d_in[5];
  const float* Wv_s = (const float*)d_in[6];
  const float* Wd_t = (const float*)d_in[7];
  const float* bd_t = (const float*)d_in[8];
  const float* Wd_s = (const float*)d_in[9];
  const float* bd_s = (const float*)d_in[10];
  float* out = (float*)d_out;
  unsigned short* qws = (unsigned short*)d_ws;  // 256*512*64*2 = 16 MiB

  hipFuncSetAttribute(reinterpret_cast<const void*>(ts_attn_fused),
                      hipFuncAttributeMaxDynamicSharedMemorySize, LDS_TOTAL_BYTES);
  ts_attn_fused<<<dim3(256), dim3(kThreads), LDS_TOTAL_BYTES, stream>>>(
      x, Wq_t, Wk_t, Wv_t, Wq_s, Wk_s, Wv_s, Wd_t, bd_t, Wd_s, bd_s, out, qws);
}

// Round 14
// 209.819 us; speedup vs baseline: 1.3287x; 1.1293x over previous
//
#include <hip/hip_runtime.h>

typedef __attribute__((ext_vector_type(8))) short short8;
typedef __attribute__((ext_vector_type(4))) short short4v;
typedef __attribute__((ext_vector_type(4))) float float4v;

#define MFMA16(a, b, c) __builtin_amdgcn_mfma_f32_16x16x32_bf16((a), (b), (c), 0, 0, 0)

constexpr int kThreads = 512;  // 8 waves; with 80 KiB LDS -> 2 blocks/CU -> 4 waves/SIMD
// GRID: 512 blocks. Block bp handles batch b = bp>>1, q-tile half h = bp&1
// (q-tiles h*16 .. h*16+15). K/V processed in TWO position-halves of 256,
// online softmax carries o/m/sum across them.
//
// LDS (ushort units), 40960 us = 81920 B total (exactly 2 per 160-KiB CU):
//   [0,     16384)  Ksw : K pos-half (256 rows). Per row 8 granules of 8 us:
//                   granule g = cp*4+quad XOR (lrow&7); content
//                   [K[pos][cp*32+quad*4+0..3], K[pos][cp*32+16+quad*4+0..3]]
//   [16384, 32768)  Vsw : V pos-half, d-major 256 us/channel:
//                   (d<<8) + (qg2<<6) + (gv<<3) + jj, gv = kpqL^(d&7)^qg2
//   [32768, 36864)  slotA : one 64x64 W matrix (staged just-in-time)
//   [36864, 40960)  slotB : one 64x64 W matrix
constexpr int LDS_TOTAL_BYTES = 81920;
// REGISTER REALITY (r10-r13, four controlled failures): 1024-thread blocks
// get a 64-VGPR budget and spill regardless of launch_bounds/waves_per_eu.
// 512-thread blocks with __launch_bounds__(512,2) allocate 120-128 VGPR
// clean (five builds). So occupancy must come from 2 blocks/CU, not a
// bigger block. 16 waves x 128 VGPR = 2048 = the per-CU VGPR pool: exact.

static __device__ __forceinline__ unsigned short f2bf(float f) {
  // native cast -> HW v_cvt_pk_bf16_f32 (RNE)
  __bf16 h = (__bf16)f;
  return __builtin_bit_cast(unsigned short, h);
}

// W staging swizzle for phase 1 (b128 frags of 8 consecutive d).
static __device__ __forceinline__ int wsw_idx(int e, int d) {
  return ((((d >> 3) << 9) + (e << 3) + (d & 7)) ^ (((d >> 3) & 3) << 3));
}

__global__ __launch_bounds__(kThreads, 2) void ts_attn_fused(
    const float* __restrict__ x, const float* __restrict__ Wq_t,
    const float* __restrict__ Wk_t, const float* __restrict__ Wv_t,
    const float* __restrict__ Wq_s, const float* __restrict__ Wk_s,
    const float* __restrict__ Wv_s, const float* __restrict__ Wd_t,
    const float* __restrict__ bd_t, const float* __restrict__ Wd_s,
    const float* __restrict__ bd_s, float* __restrict__ out,
    unsigned short* __restrict__ qws) {
  extern __shared__ __align__(16) unsigned short smem[];
  unsigned short* Ksw = smem;             // 16384 us
  unsigned short* Vsw = smem + 16384;     // 16384 us
  unsigned short* slotA = smem + 32768;   // 4096 us
  unsigned short* slotB = smem + 36864;   // 4096 us

  const int tid = threadIdx.x;
  const int wv = tid >> 6;    // wave 0..7
  const int lane = tid & 63;
  const int ln = lane & 15;   // q position within 16-tile
  const int quad = lane >> 4;
  const int e8 = ln & 7;
  const int bp = blockIdx.x;
  const int b = bp >> 1;      // batch
  const int h = bp & 1;       // q-tile half

  const float* xb = x + (size_t)b * (512 * 64);
  float* outb = out + (size_t)b * (512 * 64);
  unsigned short* qg = qws + (size_t)b * (512 * 64);  // Q bf16, slot-group order
  // (block pair shares qg but touches disjoint rows; each block reads only
  //  the rows it wrote itself -> no cross-block visibility needed)

  // Phase-2 read bases (lane-constant)
  const int kb0 = ln * 64 + ((quad ^ e8) << 3);        // K cp=0 granule
  const int kb1 = ln * 64 + (((4 + quad) ^ e8) << 3);  // K cp=1 granule
  const int vxor = (quad << 3) ^ (e8 << 3);            // V read granule XOR

  // ---- staging / compute helpers (all fully inlined) ----
  auto stageW = [&](const float* W, unsigned short* dst) {
    const int d = tid >> 3;
    const int e0 = (tid & 7) * 8;
    const float4v u = *reinterpret_cast<const float4v*>(W + d * 64 + e0);
    const float4v v = *reinterpret_cast<const float4v*>(W + d * 64 + e0 + 4);
#pragma unroll
    for (int i = 0; i < 4; ++i) dst[wsw_idx(e0 + i, d)] = f2bf(u[i]);
#pragma unroll
    for (int i = 0; i < 4; ++i) dst[wsw_idx(e0 + 4 + i, d)] = f2bf(v[i]);
  };
  auto stageWd = [&](const float* W, unsigned short* dst) {
    const int d = tid >> 3;
    const int e0 = (tid & 7) * 8;
    const int cp_ = d >> 5;
    const int c = d & 31;
    const int qd_ = (c >> 2) & 3;
    const int h_ = ((c >> 4) << 2) | (c & 3);
    const int gbase = cp_ * 4 + qd_;
    const float4v u = *reinterpret_cast<const float4v*>(W + d * 64 + e0);
    const float4v v = *reinterpret_cast<const float4v*>(W + d * 64 + e0 + 4);
#pragma unroll
    for (int i = 0; i < 4; ++i) {
      const int e = e0 + i;
      dst[e * 64 + ((gbase ^ (e & 7)) << 3) + h_] = f2bf(u[i]);
    }
#pragma unroll
    for (int i = 0; i < 4; ++i) {
      const int e = e0 + 4 + i;
      dst[e * 64 + ((gbase ^ (e & 7)) << 3) + h_] = f2bf(v[i]);
    }
  };
  auto loadX = [&](int grow, short8& xa0, short8& xa1) {
    const float4v u0 = *reinterpret_cast<const float4v*>(xb + grow * 64 + quad * 8);
    const float4v v0 = *reinterpret_cast<const float4v*>(xb + grow * 64 + quad * 8 + 4);
    const float4v u1 = *reinterpret_cast<const float4v*>(xb + grow * 64 + 32 + quad * 8);
    const float4v v1 = *reinterpret_cast<const float4v*>(xb + grow * 64 + 32 + quad * 8 + 4);
#pragma unroll
    for (int i = 0; i < 4; ++i) {
      xa0[i] = (short)f2bf(u0[i]);
      xa0[4 + i] = (short)f2bf(v0[i]);
      xa1[i] = (short)f2bf(u1[i]);
      xa1[4 + i] = (short)f2bf(v1[i]);
    }
  };
  auto mmW = [&](const unsigned short* Wl, const short8& xa0, const short8& xa1,
                 int nt) -> float4v {
    const short8 w0 = *reinterpret_cast<const short8*>(Wl + wsw_idx(nt * 16 + ln, quad * 8));
    const short8 w1 = *reinterpret_cast<const short8*>(Wl + wsw_idx(nt * 16 + ln, 32 + quad * 8));
    float4v acc = {0.f, 0.f, 0.f, 0.f};
    acc = MFMA16(w0, xa0, acc);
    acc = MFMA16(w1, xa1, acc);
    return acc;  // acc[r] = M[row][e = nt*16 + quad*4 + r]
  };
  auto writeQ = [&](int grow, int nt, float4v acc) {
    short4v pk;
#pragma unroll
    for (int r = 0; r < 4; ++r) pk[r] = (short)f2bf(acc[r]);
    *reinterpret_cast<short4v*>(qg + grow * 64 + (nt >> 1) * 32 + quad * 8 + (nt & 1) * 4) = pk;
  };
  auto writeK = [&](int lrow, int nt, float4v acc) {
    short4v pk;
#pragma unroll
    for (int r = 0; r < 4; ++r) pk[r] = (short)f2bf(acc[r]);
    const int gswz = ((nt >> 1) * 4 + quad) ^ (lrow & 7);
    *reinterpret_cast<short4v*>(Ksw + lrow * 64 + (gswz << 3) + (nt & 1) * 4) = pk;
  };
  auto writeV = [&](int lrow, int nt, float4v acc) {
    const int kpqL = lrow >> 5;        // 0..7 (local kp group)
    const int w5 = lrow & 31;
    const int jj = ((w5 >> 4) << 2) | (w5 & 3);
    const int qg2 = (w5 >> 2) & 3;
#pragma unroll
    for (int r = 0; r < 4; ++r) {
      const int d = nt * 16 + quad * 4 + r;
      const int gv = kpqL ^ (d & 7) ^ qg2;
      Vsw[(d << 8) + (qg2 << 6) + (gv << 3) + jj] = f2bf(acc[r]);
    }
  };

#pragma unroll 1
  for (int br = 0; br < 2; ++br) {
    const float* Wq = br ? Wq_s : Wq_t;
    const float* Wk = br ? Wk_s : Wk_t;
    const float* Wv = br ? Wv_s : Wv_t;
    const float* Wd = br ? Wd_s : Wd_t;

    // S0: Wq->A, Wk->B
    stageW(Wq, slotA);
    stageW(Wk, slotB);
    __syncthreads();

    // C0: Q (this block's 16 q-tiles) -> qws; K pos-half 0 -> Ksw
#pragma unroll 1
    for (int i = 0; i < 2; ++i) {
      const int grow = (h * 16 + wv + i * 8) * 16 + ln;
      short8 xa0, xa1;
      loadX(grow, xa0, xa1);
#pragma unroll
      for (int nt = 0; nt < 4; ++nt) writeQ(grow, nt, mmW(slotA, xa0, xa1, nt));
    }
#pragma unroll 1
    for (int i = 0; i < 2; ++i) {
      const int lrow = (wv + i * 8) * 16 + ln;  // grow == lrow for half 0
      short8 xa0, xa1;
      loadX(lrow, xa0, xa1);
#pragma unroll
      for (int nt = 0; nt < 4; ++nt) writeK(lrow, nt, mmW(slotB, xa0, xa1, nt));
    }
    __syncthreads();

    // S1: Wv->A ; C1: V pos-half 0 -> Vsw
    stageW(Wv, slotA);
    __syncthreads();
#pragma unroll 1
    for (int i = 0; i < 2; ++i) {
      const int lrow = (wv + i * 8) * 16 + ln;
      short8 xa0, xa1;
      loadX(lrow, xa0, xa1);
#pragma unroll
      for (int nt = 0; nt < 4; ++nt) writeV(lrow, nt, mmW(slotA, xa0, xa1, nt));
    }
    __syncthreads();

    // ---- phase 2: dual q-tiles (A: h*16+wv, B: h*16+wv+8), online softmax
    //      across the two K/V position-halves ----
    const int qtA = h * 16 + wv;
    const int qtB = h * 16 + wv + 8;
    const unsigned short* qrowA = qg + (qtA * 16 + ln) * 64;
    const unsigned short* qrowB = qg + (qtB * 16 + ln) * 64;
    const short8 qaA = *reinterpret_cast<const short8*>(qrowA + quad * 8);
    const short8 qbA = *reinterpret_cast<const short8*>(qrowA + 32 + quad * 8);
    const short8 qaB = *reinterpret_cast<const short8*>(qrowB + quad * 8);
    const short8 qbB = *reinterpret_cast<const short8*>(qrowB + 32 + quad * 8);

    float4v oA[4], oB[4];
#pragma unroll
    for (int i = 0; i < 4; ++i) {
      oA[i] = (float4v){0.f, 0.f, 0.f, 0.f};
      oB[i] = (float4v){0.f, 0.f, 0.f, 0.f};
    }
    float mrunA = -3.0e38f, mrunB = -3.0e38f;
    float sumA = 0.f, sumB = 0.f;

#pragma unroll 1
    for (int p = 0; p < 2; ++p) {
      // sweep this half's 16 k-tiles, S-window = 4 tiles
#pragma unroll 1
      for (int ch = 0; ch < 4; ++ch) {
        float4v sA[4], sB[4];
#pragma unroll
        for (int k8 = 0; k8 < 4; ++k8) {
          const int kt = ch * 4 + k8;  // local k-tile
          const short8 k0 = *reinterpret_cast<const short8*>(Ksw + kt * 1024 + kb0);
          const short8 k1 = *reinterpret_cast<const short8*>(Ksw + kt * 1024 + kb1);
          float4v aA = {0.f, 0.f, 0.f, 0.f};
          aA = MFMA16(k0, qaA, aA);
          aA = MFMA16(k1, qbA, aA);
          sA[k8] = aA;
          float4v aB = {0.f, 0.f, 0.f, 0.f};
          aB = MFMA16(k0, qaB, aB);
          aB = MFMA16(k1, qbB, aB);
          sB[k8] = aB;
        }

        float4v m4A = sA[0], m4B = sB[0];
#pragma unroll
        for (int k8 = 1; k8 < 4; ++k8)
#pragma unroll
          for (int r = 0; r < 4; ++r) {
            m4A[r] = fmaxf(m4A[r], sA[k8][r]);
            m4B[r] = fmaxf(m4B[r], sB[k8][r]);
          }
        float cmxA = fmaxf(fmaxf(m4A[0], m4A[1]), fmaxf(m4A[2], m4A[3]));
        float cmxB = fmaxf(fmaxf(m4B[0], m4B[1]), fmaxf(m4B[2], m4B[3]));
        cmxA = fmaxf(cmxA, __shfl_xor(cmxA, 16, 64));
        cmxB = fmaxf(cmxB, __shfl_xor(cmxB, 16, 64));
        cmxA = fmaxf(cmxA, __shfl_xor(cmxA, 32, 64));
        cmxB = fmaxf(cmxB, __shfl_xor(cmxB, 32, 64));

        const float mnewA = fmaxf(mrunA, cmxA);
        const float mnewB = fmaxf(mrunB, cmxB);
        const float scaleA = __expf((mrunA - mnewA) * 0.125f);  // 0 on first chunk
        const float scaleB = __expf((mrunB - mnewB) * 0.125f);
        sumA *= scaleA;
        sumB *= scaleB;
#pragma unroll
        for (int i = 0; i < 4; ++i)
#pragma unroll
          for (int r = 0; r < 4; ++r) {
            oA[i][r] *= scaleA;
            oB[i][r] *= scaleB;
          }
        const float offsA = -mnewA * 0.125f;
        const float offsB = -mnewB * 0.125f;
        mrunA = mnewA;
        mrunB = mnewB;

#pragma unroll
        for (int kp = 0; kp < 2; ++kp) {
          float pA[8], pB[8];
#pragma unroll
          for (int hh = 0; hh < 2; ++hh) {
            const int k8 = kp * 2 + hh;
#pragma unroll
            for (int r = 0; r < 4; ++r) {
              pA[hh * 4 + r] = __expf(fmaf(sA[k8][r], 0.125f, offsA));
              pB[hh * 4 + r] = __expf(fmaf(sB[k8][r], 0.125f, offsB));
            }
          }
          sumA += ((pA[0] + pA[4]) + (pA[1] + pA[5])) + ((pA[2] + pA[6]) + (pA[3] + pA[7]));
          sumB += ((pB[0] + pB[4]) + (pB[1] + pB[5])) + ((pB[2] + pB[6]) + (pB[3] + pB[7]));
          short8 pfA, pfB;
#pragma unroll
          for (int j = 0; j < 8; ++j) {
            pfA[j] = (short)f2bf(pA[j]);
            pfB[j] = (short)f2bf(pB[j]);
          }
          const int kpg = ch * 2 + kp;  // local kp group 0..7
#pragma unroll
          for (int nto = 0; nto < 4; ++nto) {
            const int vb = (nto * 16 + ln) * 256 + quad * 64;
            const short8 vf = *reinterpret_cast<const short8*>(
                Vsw + vb + (((kpg << 3) ^ vxor)));
            oA[nto] = MFMA16(vf, pfA, oA[nto]);
            oB[nto] = MFMA16(vf, pfB, oB[nto]);
          }
        }
      }

      if (p == 0) {
        // restage K/V for position-half 1 (o/m/sum stay live in registers)
        __syncthreads();
        stageW(Wk, slotA);
        stageW(Wv, slotB);
        __syncthreads();
#pragma unroll 1
        for (int i = 0; i < 2; ++i) {
          const int lrow = (wv + i * 8) * 16 + ln;
          const int grow = 256 + lrow;
          short8 xa0, xa1;
          loadX(grow, xa0, xa1);  // shared by K and V
#pragma unroll
          for (int nt = 0; nt < 4; ++nt) {
            writeK(lrow, nt, mmW(slotA, xa0, xa1, nt));
            writeV(lrow, nt, mmW(slotB, xa0, xa1, nt));
          }
        }
        __syncthreads();
      }
    }

    sumA += __shfl_xor(sumA, 16, 64);
    sumB += __shfl_xor(sumB, 16, 64);
    sumA += __shfl_xor(sumA, 32, 64);
    sumB += __shfl_xor(sumB, 32, 64);
    const float invA = 1.0f / sumA;
    const float invB = 1.0f / sumB;

    short8 of0A, of1A, of0B, of1B;
#pragma unroll
    for (int r = 0; r < 4; ++r) {
      of0A[r] = (short)f2bf(oA[0][r] * invA);
      of0A[4 + r] = (short)f2bf(oA[1][r] * invA);
      of1A[r] = (short)f2bf(oA[2][r] * invA);
      of1A[4 + r] = (short)f2bf(oA[3][r] * invA);
      of0B[r] = (short)f2bf(oB[0][r] * invB);
      of0B[4 + r] = (short)f2bf(oB[1][r] * invB);
      of1B[r] = (short)f2bf(oB[2][r] * invB);
      of1B[4 + r] = (short)f2bf(oB[3][r] * invB);
    }

    // S3: Wd -> slotA (Wd2 layout; slotA's last readers synced after C2)
    stageWd(Wd, slotA);
    __syncthreads();

    // dense: Z^T = Wd^T @ O^T; Wd frags shared A/B; float4 epilogue
#pragma unroll
    for (int nt = 0; nt < 4; ++nt) {
      const int ebase = (nt * 16 + ln) * 64;
      const short8 w0 = *reinterpret_cast<const short8*>(
          slotA + ebase + ((quad ^ e8) << 3));
      const short8 w1 = *reinterpret_cast<const short8*>(
          slotA + ebase + (((4 + quad) ^ e8) << 3));
      float4v accA = {0.f, 0.f, 0.f, 0.f};
      accA = MFMA16(w0, of0A, accA);
      accA = MFMA16(w1, of1A, accA);
      float4v accB = {0.f, 0.f, 0.f, 0.f};
      accB = MFMA16(w0, of0B, accB);
      accB = MFMA16(w1, of1B, accB);
      const int e0 = nt * 16 + quad * 4;
#pragma unroll
      for (int t = 0; t < 2; ++t) {
        const int row = (t == 0 ? qtA : qtB) * 16 + ln;
        const float4v acc = t == 0 ? accA : accB;
        float4v* op = reinterpret_cast<float4v*>(outb + row * 64 + e0);
        if (br == 0) {
          *op = acc;  // park temporal branch (sans bias)
        } else {
          const float4v bt = *reinterpret_cast<const float4v*>(bd_t + e0);
          const float4v bs = *reinterpret_cast<const float4v*>(bd_s + e0);
          const float4v parked = *op;
          const float4v xv = *reinterpret_cast<const float4v*>(xb + row * 64 + e0);
          float4v res;
#pragma unroll
          for (int r = 0; r < 4; ++r) {
            const float z = parked[r] + acc[r] + bt[r] + bs[r];
            const float gate = 1.0f / (1.0f + __expf(-z));
            res[r] = xv[r] * gate;
          }
          *op = res;
        }
      }
    }
    __syncthreads();  // protect slotA/Ksw/Vsw before next branch restages
  }
}

extern "C" void kernel_launch(void* const* d_in, const int* in_sizes, int n_in,
                              void* d_out, int out_size, void* d_ws, size_t ws_size,
                              hipStream_t stream) {
  const float* x = (const float*)d_in[0];
  const float* Wq_t = (const float*)d_in[1];
  const float* Wk_t = (const float*)d_in[2];
  const float* Wv_t = (const float*)d_in[3];
  const float* Wq_s = (const float*)d_in[4];
  const float* Wk_s = (const float*)d_in[5];
  const float* Wv_s = (const float*)d_in[6];
  const float* Wd_t = (const float*)d_in[7];
  const float* bd_t = (const float*)d_in[8];
  const float* Wd_s = (const float*)d_in[9];
  const float* bd_s = (const float*)d_in[10];
  float* out = (float*)d_out;
  unsigned short* qws = (unsigned short*)d_ws;  // 256*512*64*2 = 16 MiB

  hipFuncSetAttribute(reinterpret_cast<const void*>(ts_attn_fused),
                      hipFuncAttributeMaxDynamicSharedMemorySize, LDS_TOTAL_BYTES);
  ts_attn_fused<<<dim3(512), dim3(kThreads), LDS_TOTAL_BYTES, stream>>>(
      x, Wq_t, Wk_t, Wv_t, Wq_s, Wk_s, Wv_s, Wd_t, bd_t, Wd_s, bd_s, out, qws);
}